// Round 1
// baseline (4190.829 us; speedup 1.0000x reference)
//
#include <hip/hip_runtime.h>
#include <math.h>

#define NN 100000        // nodes
#define NE 1600000       // edges
#define MNZ 800000       // nnz per motif
#define NM 13            // motifs
// C_IN = C_OUT = D = 64; K_total = 14*64 = 896; out cols = 13*64 = 832

typedef __attribute__((ext_vector_type(8))) short short8;
typedef __attribute__((ext_vector_type(4))) float floatx4;

__device__ __forceinline__ unsigned short f2bf(float f) {
    unsigned int u = __float_as_uint(f);
    u += 0x7FFFu + ((u >> 16) & 1u);   // round-to-nearest-even
    return (unsigned short)(u >> 16);
}

// ---------------- K1: XW = x @ W_rel  (N x 64 @ 64 x 64, fp32) ----------------
__global__ __launch_bounds__(256) void k_xw(const float* __restrict__ x,
                                            const float* __restrict__ W,
                                            float* __restrict__ out) {
    __shared__ float Wl[64 * 64];
    __shared__ float xl[4][64];
    int t = threadIdx.x;
    for (int s = t; s < 4096; s += 256) Wl[s] = W[s];
    int nl = t >> 6, d = t & 63;
    int n = blockIdx.x * 4 + nl;
    xl[nl][d] = x[n * 64 + d];
    __syncthreads();
    float acc = 0.f;
#pragma unroll
    for (int k = 0; k < 64; ++k) acc = fmaf(xl[nl][k], Wl[k * 64 + d], acc);
    out[n * 64 + d] = acc;
}

// ---------------- K2: edge scatter  h[dst] += w * xw[src], deg[dst] += 1 ------
// R layout: node-major [NN][14][64]; r=0 block is h.
__global__ __launch_bounds__(256) void k_edge(const int* __restrict__ ei,
                                              const float* __restrict__ ew,
                                              const float* __restrict__ xw,
                                              float* __restrict__ R,
                                              float* __restrict__ deg) {
    long long tid = (long long)blockIdx.x * 256 + threadIdx.x;
    int e = (int)(tid >> 6);
    int lane = (int)(tid & 63);
    int s = ei[e];
    int d = ei[NE + e];
    float w = ew[e];
    atomicAdd(&R[(long long)d * 896 + lane], w * xw[(long long)s * 64 + lane]);
    if (lane == 0) atomicAdd(&deg[d], 1.0f);
}

// ---------------- K3: h = h*norm + x@root + bias ------------------------------
__global__ __launch_bounds__(256) void k_fin(const float* __restrict__ x,
                                             const float* __restrict__ root,
                                             const float* __restrict__ bias,
                                             const float* __restrict__ deg,
                                             float* __restrict__ R) {
    __shared__ float Wl[64 * 64];
    __shared__ float xl[4][64];
    int t = threadIdx.x;
    for (int s = t; s < 4096; s += 256) Wl[s] = root[s];
    int nl = t >> 6, d = t & 63;
    int n = blockIdx.x * 4 + nl;
    xl[nl][d] = x[n * 64 + d];
    __syncthreads();
    float acc = 0.f;
#pragma unroll
    for (int k = 0; k < 64; ++k) acc = fmaf(xl[nl][k], Wl[k * 64 + d], acc);
    float dg = deg[n];
    float nm = dg > 0.f ? 1.0f / dg : 0.f;
    long long idx = (long long)n * 896 + d;
    R[idx] = R[idx] * nm + acc + bias[d];
}

// ---------------- K4: motif scatter  R[dst][m+1] += val * h[src] --------------
__global__ __launch_bounds__(256) void k_motif(const int* __restrict__ msrc,
                                               const int* __restrict__ mdst,
                                               const float* __restrict__ mval,
                                               float* __restrict__ R) {
    int m = blockIdx.y;
    long long tid = (long long)blockIdx.x * 256 + threadIdx.x;
    int j = (int)(tid >> 6);
    int lane = (int)(tid & 63);
    long long base = (long long)m * MNZ + j;
    int s = msrc[base];
    int d = mdst[base];
    float v = mval[base];
    float hv = R[(long long)s * 896 + lane];                 // r=0 block (read-only here)
    atomicAdd(&R[(long long)d * 896 + (m + 1) * 64 + lane], v * hv);
}

// ---------------- K5: build WT (Wbig^T) in bf16: [832 cols][896 k] ------------
// WT[n][k] with n = 64*(i-1)+d, k = 64*r+kk:
//   0 if r==i else motif_W[i-1][ j*64+kk ][ d ],  j = r<i ? r : r-1
__global__ void k_wt(const float* __restrict__ mW, unsigned short* __restrict__ WT) {
    int n = blockIdx.y;                        // 0..831
    int k = blockIdx.x * 128 + threadIdx.x;    // 0..895
    int i = (n >> 6) + 1;
    int d = n & 63;
    int r = k >> 6;
    int kk = k & 63;
    float v = 0.f;
    if (r != i) {
        int j = (r < i) ? r : r - 1;
        v = mW[((long long)(i - 1) * 832 + (j * 64 + kk)) * 64 + d];
    }
    WT[(long long)n * 896 + k] = f2bf(v);
}

// ---------------- K6: fused GEMM + mw + attention -----------------------------
// grid (13, 782): x = motif col-block (L2-friendly: consecutive blocks share A tile),
// y = 128-row tile. Block 256 thr = 4 waves; wave w: rows w*32..w*32+31, all 64 cols.
#define BM 128
#define LDA 72   // bf16 elems per LDS row (72*2=144B, 16B aligned, 2-way banks)

__global__ __launch_bounds__(256) void k_gemm(const float* __restrict__ R,
                                              const unsigned short* __restrict__ WT,
                                              const float* __restrict__ wa,
                                              const float* __restrict__ ba,
                                              const float* __restrict__ mb,
                                              float* __restrict__ out) {
    int im1 = blockIdx.x;          // 0..12, motif i = im1+1
    int i = im1 + 1;
    int row0 = blockIdx.y * BM;
    int t = threadIdx.x;
    int w = t >> 6;
    int lane = t & 63;
    int quad = lane >> 4;
    int l16 = lane & 15;

    __shared__ __align__(16) unsigned short Al[BM * LDA];
    __shared__ __align__(16) unsigned short Bl[64 * LDA];
    __shared__ __align__(16) unsigned short waTl[64 * LDA];

    // stage wa^T once: waTl[d][k] = bf16(wa[k][d])
    for (int s = t; s < 4096; s += 256) {
        int k = s >> 6, d = s & 63;
        waTl[d * LDA + k] = f2bf(wa[s]);
    }

    floatx4 acc[2][4];   // c accumulator: [m-tile][n-tile]
    floatx4 mwa[2][4];   // mw accumulator
#pragma unroll
    for (int a = 0; a < 2; ++a)
#pragma unroll
        for (int b = 0; b < 4; ++b) { acc[a][b] = (floatx4)0.f; mwa[a][b] = (floatx4)0.f; }

    // kb 0..13: main K loop (c).  kb==14: mw pass (A chunk r=i, B = wa^T).
    for (int kb = 0; kb < 15; ++kb) {
        int kchunk = (kb < 14) ? kb : i;
        __syncthreads();
        // stage A: 128 rows x 64 k, fp32 -> bf16 (float4 global loads)
#pragma unroll
        for (int s = 0; s < 8; ++s) {
            int lin4 = t + s * 256;          // float4 index 0..2047
            int rr = lin4 >> 4;              // row 0..127
            int k4 = (lin4 & 15) * 4;        // k 0..60
            int grow = row0 + rr;
            floatx4 v = (floatx4)0.f;
            if (grow < NN) v = *(const floatx4*)&R[(long long)grow * 896 + kchunk * 64 + k4];
            unsigned short* p = &Al[rr * LDA + k4];
            p[0] = f2bf(v.x); p[1] = f2bf(v.y); p[2] = f2bf(v.z); p[3] = f2bf(v.w);
        }
        if (kb < 14) {
            // stage B chunk from WT (already bf16): 64 rows x 64 k
#pragma unroll
            for (int s = 0; s < 4; ++s) {
                int lin4 = t + s * 256;      // ushort4 index 0..1023
                int n = lin4 >> 4;
                int k4 = (lin4 & 15) * 4;
                const unsigned short* src = &WT[(long long)(im1 * 64 + n) * 896 + kb * 64 + k4];
                *(unsigned long long*)&Bl[n * LDA + k4] = *(const unsigned long long*)src;
            }
        }
        __syncthreads();
#pragma unroll
        for (int kk = 0; kk < 64; kk += 32) {
            short8 af[2];
#pragma unroll
            for (int mt = 0; mt < 2; ++mt)
                af[mt] = *(const short8*)&Al[((w * 2 + mt) * 16 + l16) * LDA + kk + quad * 8];
            if (kb < 14) {
#pragma unroll
                for (int nt = 0; nt < 4; ++nt) {
                    short8 bf = *(const short8*)&Bl[(nt * 16 + l16) * LDA + kk + quad * 8];
#pragma unroll
                    for (int mt = 0; mt < 2; ++mt)
                        acc[mt][nt] = __builtin_amdgcn_mfma_f32_16x16x32_bf16(af[mt], bf, acc[mt][nt], 0, 0, 0);
                }
            } else {
#pragma unroll
                for (int nt = 0; nt < 4; ++nt) {
                    short8 bf = *(const short8*)&waTl[(nt * 16 + l16) * LDA + kk + quad * 8];
#pragma unroll
                    for (int mt = 0; mt < 2; ++mt)
                        mwa[mt][nt] = __builtin_amdgcn_mfma_f32_16x16x32_bf16(af[mt], bf, mwa[mt][nt], 0, 0, 0);
                }
            }
        }
    }

    // epilogue: c += mb, mw += ba; att = sigmoid(sum_d mw*c); out = att*(mw-c)
#pragma unroll
    for (int mt = 0; mt < 2; ++mt) {
        float cv[4][4], mv[4][4];   // [nt][reg]
#pragma unroll
        for (int nt = 0; nt < 4; ++nt) {
            int col = nt * 16 + l16;
            float mbv = mb[im1 * 64 + col];
            float bav = ba[col];
#pragma unroll
            for (int r = 0; r < 4; ++r) {
                cv[nt][r] = acc[mt][nt][r] + mbv;
                mv[nt][r] = mwa[mt][nt][r] + bav;
            }
        }
        int grow_base = row0 + (w * 2 + mt) * 16 + quad * 4;
#pragma unroll
        for (int r = 0; r < 4; ++r) {
            float s = 0.f;
#pragma unroll
            for (int nt = 0; nt < 4; ++nt) s += mv[nt][r] * cv[nt][r];
            s += __shfl_xor(s, 1);
            s += __shfl_xor(s, 2);
            s += __shfl_xor(s, 4);
            s += __shfl_xor(s, 8);   // full 64-col row sum within the 16-lane quad group
            float att = 1.f / (1.f + __expf(-s));
            int grow = grow_base + r;
            if (grow < NN) {
#pragma unroll
                for (int nt = 0; nt < 4; ++nt)
                    out[(long long)grow * 832 + im1 * 64 + nt * 16 + l16] = att * (mv[nt][r] - cv[nt][r]);
            }
        }
    }
}

// ------------------------------------------------------------------------------
extern "C" void kernel_launch(void* const* d_in, const int* in_sizes, int n_in,
                              void* d_out, int out_size, void* d_ws, size_t ws_size,
                              hipStream_t stream) {
    const float* x    = (const float*)d_in[0];
    const int*   ei   = (const int*)d_in[1];
    const float* ew   = (const float*)d_in[2];
    const int*   msrc = (const int*)d_in[3];
    const int*   mdst = (const int*)d_in[4];
    const float* mval = (const float*)d_in[5];
    const float* Wrel = (const float*)d_in[6];
    const float* root = (const float*)d_in[7];
    const float* bias = (const float*)d_in[8];
    const float* wa   = (const float*)d_in[9];
    const float* ba   = (const float*)d_in[10];
    const float* mW   = (const float*)d_in[11];
    const float* mb   = (const float*)d_in[12];
    float* out = (float*)d_out;

    // workspace layout (~386 MB)
    float* R = (float*)d_ws;                                   // [NN][14][64] fp32
    unsigned short* WT = (unsigned short*)(R + (size_t)NN * 896); // [832][896] bf16
    float* XW = (float*)(WT + (size_t)832 * 896);              // [NN][64] fp32
    float* deg = XW + (size_t)NN * 64;                         // [NN]

    hipMemsetAsync(R, 0, sizeof(float) * (size_t)NN * 896, stream);
    hipMemsetAsync(deg, 0, sizeof(float) * (size_t)NN, stream);

    k_xw<<<NN / 4, 256, 0, stream>>>(x, Wrel, XW);
    k_edge<<<NE / 4, 256, 0, stream>>>(ei, ew, XW, R, deg);
    k_fin<<<NN / 4, 256, 0, stream>>>(x, root, bias, deg, R);
    k_motif<<<dim3(MNZ / 4, NM), 256, 0, stream>>>(msrc, mdst, mval, R);
    k_wt<<<dim3(7, 832), 128, 0, stream>>>(mW, WT);
    k_gemm<<<dim3(NM, (NN + BM - 1) / BM), 256, 0, stream>>>(R, WT, wa, ba, mb, out);
}